// Round 5
// baseline (60.690 us; speedup 1.0000x reference)
//
#include <hip/hip_runtime.h>
#include <hip/hip_bf16.h>
#include <cstdint>
#include <cstddef>

#define B_ 8
#define T_ 2048
#define E_ 1024
#define D_ 64

typedef __attribute__((ext_vector_type(8))) short bf16x8;
typedef __attribute__((ext_vector_type(4))) float f32x4;
typedef __attribute__((ext_vector_type(16))) float f32x16;
typedef __attribute__((ext_vector_type(4))) unsigned short u16x4;

#define QSCALE 0.1803368801111204f  // 0.125 * log2(e)

__device__ __forceinline__ short f2bf(float f){
    __hip_bfloat16 h = __float2bfloat16(f);
    return *reinterpret_cast<short*>(&h);
}

__device__ __forceinline__ bf16x8 cvt8v(const f32x4 a, const f32x4 b){
    bf16x8 r;
    r[0]=f2bf(a[0]); r[1]=f2bf(a[1]); r[2]=f2bf(a[2]); r[3]=f2bf(a[3]);
    r[4]=f2bf(b[0]); r[5]=f2bf(b[1]); r[6]=f2bf(b[2]); r[7]=f2bf(b[3]);
    return r;
}

// ---------- W -> MFMA-fragment-linear layout ----------
__global__ __launch_bounds__(256) void wconv_kernel(
    const float* __restrict__ Wq, const float* __restrict__ Wk,
    const float* __restrict__ Wv, __hip_bfloat16* __restrict__ Wfrag)
{
    const int g = blockIdx.x*256 + threadIdx.x;   // [0, 24576)
    const int l = g & 63;
    const int ntg = (g >> 6) % 6;
    const int cg = g / 384;
    const int n = ntg*32 + (l & 31);
    const int m = n >> 6;
    const int ncol = n & 63;
    const float* W = (m==0) ? Wq : (m==1) ? Wk : Wv;
    const float sc = (m==0) ? QSCALE : 1.0f;
    const int k0 = cg*16 + (l>>5)*8;
    bf16x8 r;
    #pragma unroll
    for (int j=0;j<8;++j)
        r[j] = f2bf(W[(size_t)(k0+j)*64 + ncol] * sc);
    *reinterpret_cast<bf16x8*>(Wfrag + (size_t)g*8) = r;
}

// ---------- QKV projection: BK=128 phases, 4-slot LDS ring, 7 barriers ----------
__global__ __launch_bounds__(256, 1) void proj_kernel(
    const float* __restrict__ x, const __hip_bfloat16* __restrict__ Wfrag,
    __hip_bfloat16* __restrict__ Qo, __hip_bfloat16* __restrict__ Ko,
    __hip_bfloat16* __restrict__ VTg)
{
    __shared__ float xs[4][64*64];   // 64 KB ring; slot = k-step & 3
    const int tid = threadIdx.x;
    const int w = tid>>6, l = tid&63;
    const int mh = w>>1, nh = w&1;
    const int l31 = l&31, kg = l>>5;
    const int rowfull = mh*32 + l31;
    const float* xp = x + (size_t)blockIdx.x*64*E_;

    f32x16 acc[3];
    #pragma unroll
    for (int i=0;i<3;++i)
        #pragma unroll
        for (int j=0;j<16;++j) acc[i][j]=0.f;

    const bf16x8* Wfp = reinterpret_cast<const bf16x8*>(Wfrag);

    bf16x8 btA[12], btB[12];
    #pragma unroll
    for (int c=0;c<4;++c)
        #pragma unroll
        for (int nt=0;nt<3;++nt)
            btA[c*3+nt] = Wfp[(size_t)(((0*4+c)*6 + (nh*3+nt))*64 + l)];

    // prologue: stage k-slices 0,1 into slots 0,1
    #pragma unroll
    for (int s=0;s<2;++s)
        #pragma unroll
        for (int i=0;i<4;++i){
            const int lin = tid + i*256;
            const int row = lin>>4, colg = lin&15;
            f32x4 v = *reinterpret_cast<const f32x4*>(xp + (size_t)row*E_ + s*64 + colg*4);
            *reinterpret_cast<f32x4*>((char*)&xs[s][0] + row*256 + ((colg ^ (row&15))<<4)) = v;
        }
    __syncthreads();

#define PROJ_COMPUTE(T, BT_CUR, BT_NXT)                                        \
    {                                                                          \
        const int t = (T);                                                     \
        if (t+1 < 16){                                                         \
            _Pragma("unroll")                                                  \
            for (int c=0;c<4;++c)                                              \
                _Pragma("unroll")                                              \
                for (int nt=0;nt<3;++nt)                                       \
                    BT_NXT[c*3+nt] = Wfp[(size_t)((((t+1)*4+c)*6 + (nh*3+nt))*64 + l)]; \
        }                                                                      \
        const char* xb = (const char*)&xs[t&3][0];                             \
        _Pragma("unroll")                                                      \
        for (int c=0;c<4;++c){                                                 \
            const int g0 = c*4 + kg*2;                                         \
            f32x4 a0 = *reinterpret_cast<const f32x4*>(xb + rowfull*256 + (((g0  ) ^ (rowfull&15))<<4)); \
            f32x4 a1 = *reinterpret_cast<const f32x4*>(xb + rowfull*256 + (((g0+1) ^ (rowfull&15))<<4)); \
            bf16x8 af = cvt8v(a0, a1);                                         \
            _Pragma("unroll")                                                  \
            for (int nt=0;nt<3;++nt)                                           \
                acc[nt] = __builtin_amdgcn_mfma_f32_32x32x16_bf16(af, BT_CUR[c*3+nt], acc[nt], 0,0,0); \
        }                                                                      \
    }

    for (int tt=0; tt<8; ++tt){
        // issue both next-phase slice loads up front
        f32x4 xa[8];
        if (tt < 7){
            #pragma unroll
            for (int s=0;s<2;++s)
                #pragma unroll
                for (int i=0;i<4;++i){
                    const int lin = tid + i*256;
                    const int row = lin>>4, colg = lin&15;
                    xa[s*4+i] = *reinterpret_cast<const f32x4*>(xp + (size_t)row*E_ + (2*tt+2+s)*64 + colg*4);
                }
        }
        PROJ_COMPUTE(2*tt,   btA, btB)
        PROJ_COMPUTE(2*tt+1, btB, btA)
        if (tt < 7){
            #pragma unroll
            for (int s=0;s<2;++s)
                #pragma unroll
                for (int i=0;i<4;++i){
                    const int lin = tid + i*256;
                    const int row = lin>>4, colg = lin&15;
                    *reinterpret_cast<f32x4*>((char*)&xs[(2*tt+2+s)&3][0] + row*256 + ((colg ^ (row&15))<<4)) = xa[s*4+i];
                }
            __syncthreads();
        }
    }
#undef PROJ_COMPUTE

    // ---- epilogue: Q and K direct; V via LDS transpose -> VTg ----
    const size_t rowbase = (size_t)blockIdx.x*64 + mh*32;
    #pragma unroll
    for (int nt=0;nt<3;++nt){
        const int nbase = (nh*3+nt)*32;
        const int mat = nbase>>6;
        if (mat < 2){
            __hip_bfloat16* dst = (mat==0)?Qo:Ko;
            const int col = (nbase&63) + l31;
            #pragma unroll
            for (int reg=0; reg<16; ++reg){
                const int mr = (reg&3) + 8*(reg>>2) + 4*kg;
                dst[(rowbase + mr)*64 + col] = __float2bfloat16(acc[nt][reg]);
            }
        }
    }
    __syncthreads();
    float* vt = (float*)&xs[0][0];   // [64][65] padded
    if (nh == 1){
        #pragma unroll
        for (int nt=1;nt<3;++nt){
            const int dbase = (nt-1)*32;
            #pragma unroll
            for (int reg=0; reg<16; ++reg){
                const int mr = mh*32 + (reg&3) + 8*(reg>>2) + 4*kg;
                vt[mr*65 + dbase + l31] = acc[nt][reg];
            }
        }
    }
    __syncthreads();
    {
        const int bb = blockIdx.x >> 5;
        const int t0 = (blockIdx.x & 31)*64;
        const int d = tid >> 2, mseg = tid & 3;
        #pragma unroll
        for (int half=0; half<2; ++half){
            bf16x8 pk;
            #pragma unroll
            for (int j=0;j<8;++j)
                pk[j] = f2bf(vt[(mseg*16 + half*8 + j)*65 + d]);
            *reinterpret_cast<bf16x8*>(VTg + (size_t)bb*64*T_ + (size_t)d*T_ + t0 + mseg*16 + half*8) = pk;
        }
    }
}

// ---------- flash attention v3: QBLK=32, paired q-tiles (p, 63-p) => uniform 33 tiles/block ----------
__global__ __launch_bounds__(256, 2) void fattn_kernel(
    const __hip_bfloat16* __restrict__ Qg, const __hip_bfloat16* __restrict__ Kg,
    const __hip_bfloat16* __restrict__ VTg, float* __restrict__ out)
{
    __shared__ __align__(16) unsigned short KT[2][2][64*64];   // [dbuf][group][kv][d] swz  32KB
    __shared__ __align__(16) unsigned short VT[2][2][64*64];   // [dbuf][group][d][kv] swz  32KB
    __shared__ __align__(16) unsigned short Pl[4][16*64];      // per-wave P               8KB

    const int tid = threadIdx.x;
    const int w = tid>>6, l = tid&63;
    const int qw = w&1, g = w>>1;          // 2 q-waves x 2 KV-parity groups
    const int l15 = l&15, lg = l>>4;

    const int lb = (blockIdx.x & 7)*32 + (blockIdx.x >> 3);   // XCD swizzle: batch per XCD
    const int b = lb >> 5;
    const int p = lb & 31;
    const size_t batchoff = (size_t)b * T_ * 64;
    const __hip_bfloat16* Kb = Kg + batchoff;
    const __hip_bfloat16* Vb = VTg + (size_t)b*64*T_;
    char* pw = (char*)&Pl[w][0];

    for (int h=0; h<2; ++h){
        const int qt = h ? p : (63 - p);   // big half first
        const int qbase = qt*32;
        const int n64 = (qt>>1) + 1;       // KV64 tiles for this q-tile
        const int R = (n64+1)>>1;
        const int qrow = qbase + qw*16 + l15;

        bf16x8 qf0 = *reinterpret_cast<const bf16x8*>(Qg + batchoff + (size_t)qrow*64 + lg*8);
        bf16x8 qf1 = *reinterpret_cast<const bf16x8*>(Qg + batchoff + (size_t)qrow*64 + 32 + lg*8);

        f32x4 o[4];
        #pragma unroll
        for (int i=0;i<4;++i) o[i] = (f32x4){0.f,0.f,0.f,0.f};
        float mrun = -1e30f, lrun = 0.f;

        // prologue: stage tiles 0 (and 1) into dbuf 0
        #pragma unroll
        for (int i=0;i<2;++i){
            const int lin = tid + i*256;
            const int srow = lin>>3, sc8 = lin&7;
            bf16x8 k0 = *reinterpret_cast<const bf16x8*>(Kb + (size_t)srow*64 + sc8*8);
            bf16x8 v0 = *reinterpret_cast<const bf16x8*>(Vb + (size_t)srow*T_ + sc8*8);
            *reinterpret_cast<bf16x8*>((char*)&KT[0][0][0] + srow*128 + ((sc8*16) ^ ((srow&7)<<4))) = k0;
            *reinterpret_cast<bf16x8*>((char*)&VT[0][0][0] + srow*128 + ((sc8*16) ^ ((srow&7)<<4))) = v0;
            if (n64 > 1){
                bf16x8 k1 = *reinterpret_cast<const bf16x8*>(Kb + (size_t)(64+srow)*64 + sc8*8);
                bf16x8 v1 = *reinterpret_cast<const bf16x8*>(Vb + (size_t)srow*T_ + 64 + sc8*8);
                *reinterpret_cast<bf16x8*>((char*)&KT[0][1][0] + srow*128 + ((sc8*16) ^ ((srow&7)<<4))) = k1;
                *reinterpret_cast<bf16x8*>((char*)&VT[0][1][0] + srow*128 + ((sc8*16) ^ ((srow&7)<<4))) = v1;
            }
        }
        __syncthreads();

        for (int r=0; r<R; ++r){
            const int rb = r&1;
            bf16x8 kn0[2], vn0[2], kn1[2], vn1[2];
            const int tn0 = 2*r+2, tn1 = 2*r+3;
            const bool ok0 = tn0 < n64, ok1 = tn1 < n64;
            if (ok0){
                #pragma unroll
                for (int i=0;i<2;++i){
                    const int lin = tid + i*256;
                    const int srow = lin>>3, sc8 = lin&7;
                    kn0[i] = *reinterpret_cast<const bf16x8*>(Kb + (size_t)(tn0*64+srow)*64 + sc8*8);
                    vn0[i] = *reinterpret_cast<const bf16x8*>(Vb + (size_t)srow*T_ + tn0*64 + sc8*8);
                }
            }
            if (ok1){
                #pragma unroll
                for (int i=0;i<2;++i){
                    const int lin = tid + i*256;
                    const int srow = lin>>3, sc8 = lin&7;
                    kn1[i] = *reinterpret_cast<const bf16x8*>(Kb + (size_t)(tn1*64+srow)*64 + sc8*8);
                    vn1[i] = *reinterpret_cast<const bf16x8*>(Vb + (size_t)srow*T_ + tn1*64 + sc8*8);
                }
            }

            const int st = 2*r + g;
            if (st < n64){
                const char* Kbuf = (const char*)&KT[rb][g][0];
                const char* Vbuf = (const char*)&VT[rb][g][0];

                f32x4 s[4];
                #pragma unroll
                for (int nt=0;nt<4;++nt) s[nt] = (f32x4){0.f,0.f,0.f,0.f};
                __builtin_amdgcn_s_setprio(1);
                #pragma unroll
                for (int ks=0;ks<2;++ks){
                    const bf16x8 qf = ks ? qf1 : qf0;
                    #pragma unroll
                    for (int nt=0;nt<4;++nt){
                        const int krow = nt*16 + l15;
                        bf16x8 kf = *reinterpret_cast<const bf16x8*>(Kbuf + krow*128 + ((ks*64 + lg*16) ^ ((krow&7)<<4)));
                        s[nt] = __builtin_amdgcn_mfma_f32_16x16x32_bf16(kf, qf, s[nt], 0,0,0);
                    }
                }
                __builtin_amdgcn_s_setprio(0);

                if (st == n64-1){
                    #pragma unroll
                    for (int nt=0;nt<4;++nt)
                        #pragma unroll
                        for (int rr=0;rr<4;++rr){
                            const int kv = st*64 + nt*16 + lg*4 + rr;
                            if (kv > qrow) s[nt][rr] = -1e30f;
                        }
                }

                float pm;
                {
                    float m0 = fmaxf(fmaxf(s[0][0],s[0][1]), fmaxf(s[0][2],s[0][3]));
                    float m1 = fmaxf(fmaxf(s[1][0],s[1][1]), fmaxf(s[1][2],s[1][3]));
                    float m2 = fmaxf(fmaxf(s[2][0],s[2][1]), fmaxf(s[2][2],s[2][3]));
                    float m3 = fmaxf(fmaxf(s[3][0],s[3][1]), fmaxf(s[3][2],s[3][3]));
                    pm = fmaxf(fmaxf(m0,m1), fmaxf(m2,m3));
                }
                pm = fmaxf(pm, __shfl_xor(pm, 16));
                pm = fmaxf(pm, __shfl_xor(pm, 32));
                if (pm > mrun + 8.0f){     // defer-max
                    const float scl = exp2f(mrun - pm);
                    mrun = pm;
                    lrun *= scl;
                    #pragma unroll
                    for (int dt=0;dt<4;++dt)
                        #pragma unroll
                        for (int j=0;j<4;++j) o[dt][j] *= scl;
                }
                float rs = 0.f;
                #pragma unroll
                for (int nt=0;nt<4;++nt)
                    #pragma unroll
                    for (int rr=0;rr<4;++rr){
                        const float pv = exp2f(s[nt][rr] - mrun);
                        s[nt][rr] = pv; rs += pv;
                    }
                rs += __shfl_xor(rs, 16);
                rs += __shfl_xor(rs, 32);
                lrun += rs;

                #pragma unroll
                for (int nt=0;nt<4;++nt){
                    u16x4 pk;
                    #pragma unroll
                    for (int rr=0;rr<4;++rr) pk[rr] = (unsigned short)f2bf(s[nt][rr]);
                    *reinterpret_cast<u16x4*>(pw + l15*128 + ((nt*32 + lg*8) ^ ((l15&7)<<4))) = pk;
                }

                __builtin_amdgcn_s_setprio(1);
                #pragma unroll
                for (int ks=0;ks<2;++ks){
                    bf16x8 pf = *reinterpret_cast<const bf16x8*>(pw + l15*128 + ((ks*64 + lg*16) ^ ((l15&7)<<4)));
                    #pragma unroll
                    for (int dt=0;dt<4;++dt){
                        const int vrow = dt*16 + l15;
                        bf16x8 vf = *reinterpret_cast<const bf16x8*>(Vbuf + vrow*128 + ((ks*64 + lg*16) ^ ((vrow&7)<<4)));
                        o[dt] = __builtin_amdgcn_mfma_f32_16x16x32_bf16(vf, pf, o[dt], 0,0,0);
                    }
                }
                __builtin_amdgcn_s_setprio(0);
            }

            if (ok0){
                #pragma unroll
                for (int i=0;i<2;++i){
                    const int lin = tid + i*256;
                    const int srow = lin>>3, sc8 = lin&7;
                    *reinterpret_cast<bf16x8*>((char*)&KT[rb^1][0][0] + srow*128 + ((sc8*16) ^ ((srow&7)<<4))) = kn0[i];
                    *reinterpret_cast<bf16x8*>((char*)&VT[rb^1][0][0] + srow*128 + ((sc8*16) ^ ((srow&7)<<4))) = vn0[i];
                }
            }
            if (ok1){
                #pragma unroll
                for (int i=0;i<2;++i){
                    const int lin = tid + i*256;
                    const int srow = lin>>3, sc8 = lin&7;
                    *reinterpret_cast<bf16x8*>((char*)&KT[rb^1][1][0] + srow*128 + ((sc8*16) ^ ((srow&7)<<4))) = kn1[i];
                    *reinterpret_cast<bf16x8*>((char*)&VT[rb^1][1][0] + srow*128 + ((sc8*16) ^ ((srow&7)<<4))) = vn1[i];
                }
            }
            __syncthreads();
        }

        // ---- merge group1 into group0, write out ----
        float* Obuf = (float*)&KT[0][0][0];   // 8 KB: [32][64] f32
        float* Mbuf = (float*)&VT[0][0][0];
        float* Lbuf = Mbuf + 32;
        const int ql = qw*16 + l15;
        if (g == 1){
            #pragma unroll
            for (int dt=0;dt<4;++dt)
                *reinterpret_cast<f32x4*>(&Obuf[ql*64 + dt*16 + lg*4]) = o[dt];
            if (lg == 0){ Mbuf[ql] = mrun; Lbuf[ql] = lrun; }
        }
        __syncthreads();
        if (g == 0){
            const float m1 = Mbuf[ql], l1 = Lbuf[ql];
            const float m = fmaxf(mrun, m1);
            const float a0 = exp2f(mrun - m), a1 = exp2f(m1 - m);
            const float inv = 1.0f/(lrun*a0 + l1*a1);
            #pragma unroll
            for (int dt=0;dt<4;++dt){
                f32x4 v1 = *reinterpret_cast<f32x4*>(&Obuf[ql*64 + dt*16 + lg*4]);
                f32x4 res;
                #pragma unroll
                for (int j=0;j<4;++j) res[j] = (o[dt][j]*a0 + v1[j]*a1)*inv;
                *reinterpret_cast<f32x4*>(out + batchoff + (size_t)qrow*64 + dt*16 + lg*4) = res;
            }
        }
        __syncthreads();   // before next half's restage
    }
}

extern "C" void kernel_launch(void* const* d_in, const int* in_sizes, int n_in,
                              void* d_out, int out_size, void* d_ws, size_t ws_size,
                              hipStream_t stream) {
    const float* x  = (const float*)d_in[0];
    const float* Wq = (const float*)d_in[1];
    const float* Wk = (const float*)d_in[2];
    const float* Wv = (const float*)d_in[3];
    float* out = (float*)d_out;

    __hip_bfloat16* Wfrag = (__hip_bfloat16*)d_ws;              // 384 KB
    __hip_bfloat16* Qb  = Wfrag + (size_t)24576*8;              // [B*T,64] (pre-scaled)
    __hip_bfloat16* Kb  = Qb + (size_t)B_*T_*64;                // [B*T,64]
    __hip_bfloat16* VTb = Kb + (size_t)B_*T_*64;                // [B][64][T]

    wconv_kernel<<<96, 256, 0, stream>>>(Wq, Wk, Wv, Wfrag);
    proj_kernel<<<(B_*T_)/64, 256, 0, stream>>>(x, Wfrag, Qb, Kb, VTb);
    fattn_kernel<<<256, 256, 0, stream>>>(Qb, Kb, VTb, out);
}

// Round 6
// 57.217 us; speedup vs baseline: 1.0607x; 1.0607x over previous
//
#include <hip/hip_runtime.h>
#include <hip/hip_bf16.h>
#include <cstdint>
#include <cstddef>

#define B_ 8
#define T_ 2048
#define E_ 1024
#define D_ 64

typedef __attribute__((ext_vector_type(8))) short bf16x8;
typedef __attribute__((ext_vector_type(4))) float f32x4;
typedef __attribute__((ext_vector_type(16))) float f32x16;
typedef __attribute__((ext_vector_type(4))) unsigned short u16x4;

#define QSCALE 0.1803368801111204f  // 0.125 * log2(e)

__device__ __forceinline__ short f2bf(float f){
    __hip_bfloat16 h = __float2bfloat16(f);
    return *reinterpret_cast<short*>(&h);
}

__device__ __forceinline__ bf16x8 cvt8v(const f32x4 a, const f32x4 b){
    bf16x8 r;
    r[0]=f2bf(a[0]); r[1]=f2bf(a[1]); r[2]=f2bf(a[2]); r[3]=f2bf(a[3]);
    r[4]=f2bf(b[0]); r[5]=f2bf(b[1]); r[6]=f2bf(b[2]); r[7]=f2bf(b[3]);
    return r;
}

// ---------- W -> MFMA-fragment-linear layout (unchanged) ----------
__global__ __launch_bounds__(256) void wconv_kernel(
    const float* __restrict__ Wq, const float* __restrict__ Wk,
    const float* __restrict__ Wv, __hip_bfloat16* __restrict__ Wfrag)
{
    const int g = blockIdx.x*256 + threadIdx.x;   // [0, 24576)
    const int l = g & 63;
    const int ntg = (g >> 6) % 6;
    const int cg = g / 384;
    const int n = ntg*32 + (l & 31);
    const int m = n >> 6;
    const int ncol = n & 63;
    const float* W = (m==0) ? Wq : (m==1) ? Wk : Wv;
    const float sc = (m==0) ? QSCALE : 1.0f;
    const int k0 = cg*16 + (l>>5)*8;
    bf16x8 r;
    #pragma unroll
    for (int j=0;j<8;++j)
        r[j] = f2bf(W[(size_t)(k0+j)*64 + ncol] * sc);
    *reinterpret_cast<bf16x8*>(Wfrag + (size_t)g*8) = r;
}

// ---------- QKV projection v3: 32 rows/block, 6 waves (1 n-tile each), 2 blocks/CU ----------
__global__ __launch_bounds__(384, 3) void proj_kernel(
    const float* __restrict__ x, const __hip_bfloat16* __restrict__ Wfrag,
    __hip_bfloat16* __restrict__ Qo, __hip_bfloat16* __restrict__ Ko,
    __hip_bfloat16* __restrict__ VTg)
{
    __shared__ float xs[2][32*64];   // 16 KB dbuf, granule-swizzled
    const int tid = threadIdx.x;
    const int w = tid>>6, l = tid&63;
    const int l31 = l&31, kg = l>>5;
    const float* xp = x + (size_t)blockIdx.x*32*E_;

    f32x16 acc;
    #pragma unroll
    for (int j=0;j<16;++j) acc[j]=0.f;

    const bf16x8* Wfp = reinterpret_cast<const bf16x8*>(Wfrag);

    bf16x8 btA[4], btB[4];
    #pragma unroll
    for (int c=0;c<4;++c)
        btA[c] = Wfp[(size_t)(((0*4+c)*6 + w)*64 + l)];

    // prologue: stage k-slice 0
    if (tid < 256){
        #pragma unroll
        for (int i=0;i<2;++i){
            const int lin = tid + i*256;
            const int row = lin>>4, colg = lin&15;
            f32x4 v = *reinterpret_cast<const f32x4*>(xp + (size_t)row*E_ + colg*4);
            *reinterpret_cast<f32x4*>((char*)&xs[0][0] + row*256 + ((colg ^ (row&15))<<4)) = v;
        }
    }
    __syncthreads();

#define PSTEP(T, BC, BN)                                                       \
    {                                                                          \
        const int t = (T);                                                     \
        if (t+1 < 16){                                                         \
            _Pragma("unroll")                                                  \
            for (int c=0;c<4;++c)                                              \
                BN[c] = Wfp[(size_t)((((t+1)*4+c)*6 + w)*64 + l)];             \
        }                                                                      \
        f32x4 xa0, xa1;                                                        \
        if (t+1 < 16 && tid < 256){                                            \
            xa0 = *reinterpret_cast<const f32x4*>(xp + (size_t)(tid>>4)*E_ + (t+1)*64 + (tid&15)*4); \
            xa1 = *reinterpret_cast<const f32x4*>(xp + (size_t)((tid+256)>>4)*E_ + (t+1)*64 + (tid&15)*4); \
        }                                                                      \
        const char* xb = (const char*)&xs[t&1][0];                             \
        _Pragma("unroll")                                                      \
        for (int c=0;c<4;++c){                                                 \
            const int g0 = c*4 + kg*2;                                         \
            f32x4 a0 = *reinterpret_cast<const f32x4*>(xb + l31*256 + (((g0  ) ^ (l31&15))<<4)); \
            f32x4 a1 = *reinterpret_cast<const f32x4*>(xb + l31*256 + (((g0+1) ^ (l31&15))<<4)); \
            bf16x8 af = cvt8v(a0, a1);                                         \
            acc = __builtin_amdgcn_mfma_f32_32x32x16_bf16(af, BC[c], acc, 0,0,0); \
        }                                                                      \
        if (t+1 < 16){                                                         \
            if (tid < 256){                                                    \
                char* xd = (char*)&xs[(t+1)&1][0];                             \
                *reinterpret_cast<f32x4*>(xd + (tid>>4)*256 + (((tid&15) ^ ((tid>>4)&15))<<4)) = xa0; \
                *reinterpret_cast<f32x4*>(xd + ((tid+256)>>4)*256 + (((tid&15) ^ (((tid+256)>>4)&15))<<4)) = xa1; \
            }                                                                  \
            __syncthreads();                                                   \
        }                                                                      \
    }

    for (int t2=0; t2<8; ++t2){
        PSTEP(2*t2,   btA, btB)
        PSTEP(2*t2+1, btB, btA)
    }
#undef PSTEP

    // ---- epilogue: waves 0,1 -> Q; 2,3 -> K; 4,5 -> V (transposed via LDS) ----
    const size_t rowBase = (size_t)blockIdx.x*32;
    const int mat = w>>1;
    const int col = (w&1)*32 + l31;
    if (mat < 2){
        __hip_bfloat16* dst = (mat==0) ? Qo : Ko;
        #pragma unroll
        for (int reg=0; reg<16; ++reg){
            const int mr = (reg&3) + 8*(reg>>2) + 4*kg;
            dst[(rowBase + mr)*64 + col] = __float2bfloat16(acc[reg]);
        }
    }
    __syncthreads();
    float* vt = (float*)&xs[0][0];   // [32][65] padded
    if (mat == 2){
        #pragma unroll
        for (int reg=0; reg<16; ++reg){
            const int mr = (reg&3) + 8*(reg>>2) + 4*kg;
            vt[mr*65 + col] = acc[reg];
        }
    }
    __syncthreads();
    if (tid < 256){
        const int bb = blockIdx.x >> 6;
        const int t0 = (blockIdx.x & 63)*32;
        const int d = tid>>2, rseg = tid&3;
        bf16x8 pk;
        #pragma unroll
        for (int j=0;j<8;++j)
            pk[j] = f2bf(vt[(rseg*8+j)*65 + d]);
        *reinterpret_cast<bf16x8*>(VTg + (size_t)bb*64*T_ + (size_t)d*T_ + t0 + rseg*8) = pk;
    }
}

// ---------- flash attention v4: barrier-free, stripe-pair blocks, KV-split waves ----------
// 512 blocks x 256 thr. Block = batch (blockIdx&7) x stripe-pair p (blockIdx>>3).
// Stripes sA=p, sB=127-p (16 q-rows each); nA+nB == 33 KV64-tiles, split round-robin
// over 4 waves. K/V^T frags direct from L2-resident global; no barriers until merge.
__global__ __launch_bounds__(256, 2) void fattn_kernel(
    const __hip_bfloat16* __restrict__ Qg, const __hip_bfloat16* __restrict__ Kg,
    const __hip_bfloat16* __restrict__ VTg, float* __restrict__ out)
{
    __shared__ __align__(16) unsigned short Pl[4][16*64];   // 8 KB per-wave P
    __shared__ float Morg[4][2][16];
    __shared__ float Lorg[4][2][16];
    __shared__ __align__(16) float Oorg[4][2][16*64];       // 32 KB partials

    const int tid = threadIdx.x;
    const int w = tid>>6, l = tid&63;
    const int l15 = l&15, lg = l>>4;

    const int b = blockIdx.x & 7;          // XCD-batch affinity
    const int p = blockIdx.x >> 3;         // 0..63
    const int sA = p, sB = 127 - p;
    const int nA = (sA>>2) + 1, nB = (sB>>2) + 1;   // KV64 tiles per stripe
    const int NU = nA + nB;                // == 33
    const size_t batchoff = (size_t)b * T_ * 64;
    const __hip_bfloat16* Kb = Kg + batchoff;
    const __hip_bfloat16* Vb = VTg + (size_t)b*64*T_;
    char* pw = (char*)&Pl[w][0];

    const int qrA = sA*16 + l15, qrB = sB*16 + l15;
    const bf16x8 qA0 = *reinterpret_cast<const bf16x8*>(Qg + batchoff + (size_t)qrA*64 + lg*8);
    const bf16x8 qA1 = *reinterpret_cast<const bf16x8*>(Qg + batchoff + (size_t)qrA*64 + 32 + lg*8);
    const bf16x8 qB0 = *reinterpret_cast<const bf16x8*>(Qg + batchoff + (size_t)qrB*64 + lg*8);
    const bf16x8 qB1 = *reinterpret_cast<const bf16x8*>(Qg + batchoff + (size_t)qrB*64 + 32 + lg*8);

    f32x4 oA[4], oB[4];
    #pragma unroll
    for (int i=0;i<4;++i){ oA[i] = (f32x4){0.f,0.f,0.f,0.f}; oB[i] = (f32x4){0.f,0.f,0.f,0.f}; }
    float mA = -1e30f, lA = 0.f, mB = -1e30f, lB = 0.f;

    bf16x8 kf[8], vf[8];

    // prologue: K frags for first unit
    {
        const int u0 = w;
        const int kv0 = (u0 < nA ? u0 : u0 - nA) * 64;
        #pragma unroll
        for (int ks=0;ks<2;++ks)
            #pragma unroll
            for (int nt=0;nt<4;++nt)
                kf[ks*4+nt] = *reinterpret_cast<const bf16x8*>(Kb + (size_t)(kv0 + nt*16 + l15)*64 + ks*32 + lg*8);
    }

    auto body = [&](f32x4 (&o)[4], float &mrun, float &lrun,
                    const bf16x8 &qf0, const bf16x8 &qf1,
                    int qrow, int kv0, bool diag, bool hasN, int kv0n)
    {
        // ---- S^T = mfma(K, Q) ----
        f32x4 s4[4];
        #pragma unroll
        for (int nt=0;nt<4;++nt) s4[nt] = (f32x4){0.f,0.f,0.f,0.f};
        __builtin_amdgcn_s_setprio(1);
        #pragma unroll
        for (int ks=0;ks<2;++ks){
            const bf16x8 qf = ks ? qf1 : qf0;
            #pragma unroll
            for (int nt=0;nt<4;++nt)
                s4[nt] = __builtin_amdgcn_mfma_f32_16x16x32_bf16(kf[ks*4+nt], qf, s4[nt], 0,0,0);
        }
        __builtin_amdgcn_s_setprio(0);

        // prefetch next unit's K into kf (WAR after QK issue; hidden under softmax+PV)
        if (hasN){
            #pragma unroll
            for (int ks=0;ks<2;++ks)
                #pragma unroll
                for (int nt=0;nt<4;++nt)
                    kf[ks*4+nt] = *reinterpret_cast<const bf16x8*>(Kb + (size_t)(kv0n + nt*16 + l15)*64 + ks*32 + lg*8);
        }

        if (diag){
            #pragma unroll
            for (int nt=0;nt<4;++nt)
                #pragma unroll
                for (int rr=0;rr<4;++rr){
                    const int kv = kv0 + nt*16 + lg*4 + rr;
                    if (kv > qrow) s4[nt][rr] = -1e30f;
                }
        }

        // ---- per-lane softmax (q = l15); reduce over lg via 2 shfls ----
        float pm;
        {
            float m0 = fmaxf(fmaxf(s4[0][0],s4[0][1]), fmaxf(s4[0][2],s4[0][3]));
            float m1 = fmaxf(fmaxf(s4[1][0],s4[1][1]), fmaxf(s4[1][2],s4[1][3]));
            float m2 = fmaxf(fmaxf(s4[2][0],s4[2][1]), fmaxf(s4[2][2],s4[2][3]));
            float m3 = fmaxf(fmaxf(s4[3][0],s4[3][1]), fmaxf(s4[3][2],s4[3][3]));
            pm = fmaxf(fmaxf(m0,m1), fmaxf(m2,m3));
        }
        pm = fmaxf(pm, __shfl_xor(pm, 16));
        pm = fmaxf(pm, __shfl_xor(pm, 32));
        if (pm > mrun + 8.0f){     // defer-max (T13)
            const float scl = exp2f(mrun - pm);
            mrun = pm; lrun *= scl;
            #pragma unroll
            for (int dt=0;dt<4;++dt)
                #pragma unroll
                for (int j=0;j<4;++j) o[dt][j] *= scl;
        }
        float rs = 0.f;
        #pragma unroll
        for (int nt=0;nt<4;++nt)
            #pragma unroll
            for (int rr=0;rr<4;++rr){
                const float pv = exp2f(s4[nt][rr] - mrun);
                s4[nt][rr] = pv; rs += pv;
            }
        rs += __shfl_xor(rs, 16);
        rs += __shfl_xor(rs, 32);
        lrun += rs;

        // ---- P -> per-wave LDS (8B packed, swizzled) ----
        #pragma unroll
        for (int nt=0;nt<4;++nt){
            u16x4 pk;
            #pragma unroll
            for (int rr=0;rr<4;++rr) pk[rr] = (unsigned short)f2bf(s4[nt][rr]);
            *reinterpret_cast<u16x4*>(pw + l15*128 + ((nt*32 + lg*8) ^ ((l15&7)<<4))) = pk;
        }

        // ---- O^T += mfma(V^T, P^T) ----
        __builtin_amdgcn_s_setprio(1);
        #pragma unroll
        for (int ks=0;ks<2;++ks){
            bf16x8 pf = *reinterpret_cast<const bf16x8*>(pw + l15*128 + ((ks*64 + lg*16) ^ ((l15&7)<<4)));
            #pragma unroll
            for (int dt=0;dt<4;++dt)
                o[dt] = __builtin_amdgcn_mfma_f32_16x16x32_bf16(vf[ks*4+dt], pf, o[dt], 0,0,0);
        }
        __builtin_amdgcn_s_setprio(0);
    };

    for (int u = w; u < NU; u += 4){
        const bool isA = (u < nA);
        const int kvt = isA ? u : (u - nA);
        const int kv0 = kvt*64;
        const bool diag = isA ? (kvt == nA-1) : (kvt == nB-1);

        // V^T frags for this unit (in flight during QK + softmax)
        #pragma unroll
        for (int ks=0;ks<2;++ks)
            #pragma unroll
            for (int dt=0;dt<4;++dt)
                vf[ks*4+dt] = *reinterpret_cast<const bf16x8*>(Vb + (size_t)(dt*16+l15)*T_ + kv0 + ks*32 + lg*8);

        const int un = u + 4;
        const bool hasN = un < NU;
        const int kv0n = hasN ? ((un < nA ? un : un - nA) * 64) : 0;

        if (isA) body(oA, mA, lA, qA0, qA1, qrA, kv0, diag, hasN, kv0n);
        else     body(oB, mB, lB, qB0, qB1, qrB, kv0, diag, hasN, kv0n);
    }

    // ---- merge 4 wave-partials per stripe ----
    #pragma unroll
    for (int dt=0;dt<4;++dt){
        *reinterpret_cast<f32x4*>(&Oorg[w][0][l15*64 + dt*16 + lg*4]) = oA[dt];
        *reinterpret_cast<f32x4*>(&Oorg[w][1][l15*64 + dt*16 + lg*4]) = oB[dt];
    }
    if (lg == 0){
        Morg[w][0][l15] = mA; Lorg[w][0][l15] = lA;
        Morg[w][1][l15] = mB; Lorg[w][1][l15] = lB;
    }
    __syncthreads();
    {
        const int h = tid>>7, q = (tid>>3)&15, d0 = (tid&7)*8;
        const float m0=Morg[0][h][q], m1=Morg[1][h][q], m2=Morg[2][h][q], m3=Morg[3][h][q];
        const float M = fmaxf(fmaxf(m0,m1), fmaxf(m2,m3));
        const float a0=exp2f(m0-M), a1=exp2f(m1-M), a2=exp2f(m2-M), a3=exp2f(m3-M);
        const float L = a0*Lorg[0][h][q] + a1*Lorg[1][h][q] + a2*Lorg[2][h][q] + a3*Lorg[3][h][q];
        const float inv = 1.0f / L;
        const int s = h ? sB : sA;
        float* op = out + batchoff + (size_t)(s*16 + q)*64 + d0;
        #pragma unroll
        for (int j=0;j<8;++j){
            const float v = a0*Oorg[0][h][q*64+d0+j] + a1*Oorg[1][h][q*64+d0+j]
                          + a2*Oorg[2][h][q*64+d0+j] + a3*Oorg[3][h][q*64+d0+j];
            op[j] = v * inv;
        }
    }
}

extern "C" void kernel_launch(void* const* d_in, const int* in_sizes, int n_in,
                              void* d_out, int out_size, void* d_ws, size_t ws_size,
                              hipStream_t stream) {
    const float* x  = (const float*)d_in[0];
    const float* Wq = (const float*)d_in[1];
    const float* Wk = (const float*)d_in[2];
    const float* Wv = (const float*)d_in[3];
    float* out = (float*)d_out;

    __hip_bfloat16* Wfrag = (__hip_bfloat16*)d_ws;              // 384 KB
    __hip_bfloat16* Qb  = Wfrag + (size_t)24576*8;              // [B*T,64] (pre-scaled)
    __hip_bfloat16* Kb  = Qb + (size_t)B_*T_*64;                // [B*T,64]
    __hip_bfloat16* VTb = Kb + (size_t)B_*T_*64;                // [B][64][T]

    wconv_kernel<<<96, 256, 0, stream>>>(Wq, Wk, Wv, Wfrag);
    proj_kernel<<<512, 384, 0, stream>>>(x, Wfrag, Qb, Kb, VTb);
    fattn_kernel<<<512, 256, 0, stream>>>(Qb, Kb, VTb, out);
}

// Round 7
// 56.802 us; speedup vs baseline: 1.0685x; 1.0073x over previous
//
#include <hip/hip_runtime.h>
#include <hip/hip_bf16.h>
#include <cstdint>
#include <cstddef>

#define B_ 8
#define T_ 2048
#define E_ 1024
#define D_ 64

typedef __attribute__((ext_vector_type(8))) short bf16x8;
typedef __attribute__((ext_vector_type(4))) float f32x4;
typedef __attribute__((ext_vector_type(16))) float f32x16;
typedef __attribute__((ext_vector_type(4))) unsigned short u16x4;

#define QSCALE 0.1803368801111204f  // 0.125 * log2(e)

__device__ __forceinline__ short f2bf(float f){
    __hip_bfloat16 h = __float2bfloat16(f);
    return *reinterpret_cast<short*>(&h);
}

__device__ __forceinline__ bf16x8 cvt8v(const f32x4 a, const f32x4 b){
    bf16x8 r;
    r[0]=f2bf(a[0]); r[1]=f2bf(a[1]); r[2]=f2bf(a[2]); r[3]=f2bf(a[3]);
    r[4]=f2bf(b[0]); r[5]=f2bf(b[1]); r[6]=f2bf(b[2]); r[7]=f2bf(b[3]);
    return r;
}

// ---------- W -> MFMA-fragment-linear layout (unchanged) ----------
__global__ __launch_bounds__(256) void wconv_kernel(
    const float* __restrict__ Wq, const float* __restrict__ Wk,
    const float* __restrict__ Wv, __hip_bfloat16* __restrict__ Wfrag)
{
    const int g = blockIdx.x*256 + threadIdx.x;   // [0, 24576)
    const int l = g & 63;
    const int ntg = (g >> 6) % 6;
    const int cg = g / 384;
    const int n = ntg*32 + (l & 31);
    const int m = n >> 6;
    const int ncol = n & 63;
    const float* W = (m==0) ? Wq : (m==1) ? Wk : Wv;
    const float sc = (m==0) ? QSCALE : 1.0f;
    const int k0 = cg*16 + (l>>5)*8;
    bf16x8 r;
    #pragma unroll
    for (int j=0;j<8;++j)
        r[j] = f2bf(W[(size_t)(k0+j)*64 + ncol] * sc);
    *reinterpret_cast<bf16x8*>(Wfrag + (size_t)g*8) = r;
}

// ---------- QKV projection v4: x staged in LDS as BF16 (convert once), lean MFMA loop ----------
__global__ __launch_bounds__(384, 3) void proj_kernel(
    const float* __restrict__ x, const __hip_bfloat16* __restrict__ Wfrag,
    __hip_bfloat16* __restrict__ Qo, __hip_bfloat16* __restrict__ Ko,
    __hip_bfloat16* __restrict__ VTg)
{
    __shared__ __align__(16) unsigned short xs[2][32*64];   // 8 KB dbuf, bf16, XOR-swizzled
    __shared__ float vt[32*65];                             // 8.3 KB V-transpose scratch
    const int tid = threadIdx.x;
    const int w = tid>>6, l = tid&63;
    const int l31 = l&31, kg = l>>5;
    const float* xp = x + (size_t)blockIdx.x*32*E_;

    f32x16 acc;
    #pragma unroll
    for (int j=0;j<16;++j) acc[j]=0.f;

    const bf16x8* Wfp = reinterpret_cast<const bf16x8*>(Wfrag);

    bf16x8 btA[4], btB[4];
    #pragma unroll
    for (int c=0;c<4;++c)
        btA[c] = Wfp[(size_t)(((0*4+c)*6 + w)*64 + l)];

    const int srow = tid>>3, sc8 = tid&7;   // stager coords (tid<256)

    // prologue: stage k-slice 0 as bf16
    if (tid < 256){
        f32x4 v0 = *reinterpret_cast<const f32x4*>(xp + (size_t)srow*E_ + sc8*8);
        f32x4 v1 = *reinterpret_cast<const f32x4*>(xp + (size_t)srow*E_ + sc8*8 + 4);
        *reinterpret_cast<bf16x8*>((char*)&xs[0][0] + srow*128 + ((sc8*16) ^ ((srow&7)<<4))) = cvt8v(v0, v1);
    }
    __syncthreads();

#define PSTEP(T, BC, BN)                                                       \
    {                                                                          \
        const int t = (T);                                                     \
        if (t+1 < 16){                                                         \
            _Pragma("unroll")                                                  \
            for (int c=0;c<4;++c)                                              \
                BN[c] = Wfp[(size_t)((((t+1)*4+c)*6 + w)*64 + l)];             \
        }                                                                      \
        f32x4 xa0, xa1;                                                        \
        if (t+1 < 16 && tid < 256){                                            \
            xa0 = *reinterpret_cast<const f32x4*>(xp + (size_t)srow*E_ + (t+1)*64 + sc8*8);     \
            xa1 = *reinterpret_cast<const f32x4*>(xp + (size_t)srow*E_ + (t+1)*64 + sc8*8 + 4); \
        }                                                                      \
        const char* xb = (const char*)&xs[t&1][0];                             \
        _Pragma("unroll")                                                      \
        for (int c=0;c<4;++c){                                                 \
            bf16x8 af = *reinterpret_cast<const bf16x8*>(xb + l31*128 + (((c*32 + kg*16)) ^ ((l31&7)<<4))); \
            acc = __builtin_amdgcn_mfma_f32_32x32x16_bf16(af, BC[c], acc, 0,0,0); \
        }                                                                      \
        if (t+1 < 16){                                                         \
            if (tid < 256)                                                     \
                *reinterpret_cast<bf16x8*>((char*)&xs[(t+1)&1][0] + srow*128 + ((sc8*16) ^ ((srow&7)<<4))) = cvt8v(xa0, xa1); \
            __syncthreads();                                                   \
        }                                                                      \
    }

    for (int t2=0; t2<8; ++t2){
        PSTEP(2*t2,   btA, btB)
        PSTEP(2*t2+1, btB, btA)
    }
#undef PSTEP

    // ---- epilogue: waves 0,1 -> Q; 2,3 -> K; 4,5 -> V (transposed via LDS) ----
    const size_t rowBase = (size_t)blockIdx.x*32;
    const int mat = w>>1;
    const int col = (w&1)*32 + l31;
    if (mat < 2){
        __hip_bfloat16* dst = (mat==0) ? Qo : Ko;
        #pragma unroll
        for (int reg=0; reg<16; ++reg){
            const int mr = (reg&3) + 8*(reg>>2) + 4*kg;
            dst[(rowBase + mr)*64 + col] = __float2bfloat16(acc[reg]);
        }
    }
    if (mat == 2){
        #pragma unroll
        for (int reg=0; reg<16; ++reg){
            const int mr = (reg&3) + 8*(reg>>2) + 4*kg;
            vt[mr*65 + col] = acc[reg];
        }
    }
    __syncthreads();
    if (tid < 256){
        const int bb = blockIdx.x >> 6;
        const int t0 = (blockIdx.x & 63)*32;
        const int d = tid>>2, rseg = tid&3;
        bf16x8 pk;
        #pragma unroll
        for (int j=0;j<8;++j)
            pk[j] = f2bf(vt[(rseg*8+j)*65 + d]);
        *reinterpret_cast<bf16x8*>(VTg + (size_t)bb*64*T_ + (size_t)d*T_ + t0 + rseg*8) = pk;
    }
}

// ---------- flash attention v4 (UNCHANGED from R6): barrier-free, stripe-pair, KV-split ----------
__global__ __launch_bounds__(256, 2) void fattn_kernel(
    const __hip_bfloat16* __restrict__ Qg, const __hip_bfloat16* __restrict__ Kg,
    const __hip_bfloat16* __restrict__ VTg, float* __restrict__ out)
{
    __shared__ __align__(16) unsigned short Pl[4][16*64];   // 8 KB per-wave P
    __shared__ float Morg[4][2][16];
    __shared__ float Lorg[4][2][16];
    __shared__ __align__(16) float Oorg[4][2][16*64];       // 32 KB partials

    const int tid = threadIdx.x;
    const int w = tid>>6, l = tid&63;
    const int l15 = l&15, lg = l>>4;

    const int b = blockIdx.x & 7;          // XCD-batch affinity
    const int p = blockIdx.x >> 3;         // 0..63
    const int sA = p, sB = 127 - p;
    const int nA = (sA>>2) + 1, nB = (sB>>2) + 1;
    const int NU = nA + nB;                // == 33
    const size_t batchoff = (size_t)b * T_ * 64;
    const __hip_bfloat16* Kb = Kg + batchoff;
    const __hip_bfloat16* Vb = VTg + (size_t)b*64*T_;
    char* pw = (char*)&Pl[w][0];

    const int qrA = sA*16 + l15, qrB = sB*16 + l15;
    const bf16x8 qA0 = *reinterpret_cast<const bf16x8*>(Qg + batchoff + (size_t)qrA*64 + lg*8);
    const bf16x8 qA1 = *reinterpret_cast<const bf16x8*>(Qg + batchoff + (size_t)qrA*64 + 32 + lg*8);
    const bf16x8 qB0 = *reinterpret_cast<const bf16x8*>(Qg + batchoff + (size_t)qrB*64 + lg*8);
    const bf16x8 qB1 = *reinterpret_cast<const bf16x8*>(Qg + batchoff + (size_t)qrB*64 + 32 + lg*8);

    f32x4 oA[4], oB[4];
    #pragma unroll
    for (int i=0;i<4;++i){ oA[i] = (f32x4){0.f,0.f,0.f,0.f}; oB[i] = (f32x4){0.f,0.f,0.f,0.f}; }
    float mA = -1e30f, lA = 0.f, mB = -1e30f, lB = 0.f;

    bf16x8 kf[8], vf[8];

    {
        const int u0 = w;
        const int kv0 = (u0 < nA ? u0 : u0 - nA) * 64;
        #pragma unroll
        for (int ks=0;ks<2;++ks)
            #pragma unroll
            for (int nt=0;nt<4;++nt)
                kf[ks*4+nt] = *reinterpret_cast<const bf16x8*>(Kb + (size_t)(kv0 + nt*16 + l15)*64 + ks*32 + lg*8);
    }

    auto body = [&](f32x4 (&o)[4], float &mrun, float &lrun,
                    const bf16x8 &qf0, const bf16x8 &qf1,
                    int qrow, int kv0, bool diag, bool hasN, int kv0n)
    {
        f32x4 s4[4];
        #pragma unroll
        for (int nt=0;nt<4;++nt) s4[nt] = (f32x4){0.f,0.f,0.f,0.f};
        __builtin_amdgcn_s_setprio(1);
        #pragma unroll
        for (int ks=0;ks<2;++ks){
            const bf16x8 qf = ks ? qf1 : qf0;
            #pragma unroll
            for (int nt=0;nt<4;++nt)
                s4[nt] = __builtin_amdgcn_mfma_f32_16x16x32_bf16(kf[ks*4+nt], qf, s4[nt], 0,0,0);
        }
        __builtin_amdgcn_s_setprio(0);

        if (hasN){
            #pragma unroll
            for (int ks=0;ks<2;++ks)
                #pragma unroll
                for (int nt=0;nt<4;++nt)
                    kf[ks*4+nt] = *reinterpret_cast<const bf16x8*>(Kb + (size_t)(kv0n + nt*16 + l15)*64 + ks*32 + lg*8);
        }

        if (diag){
            #pragma unroll
            for (int nt=0;nt<4;++nt)
                #pragma unroll
                for (int rr=0;rr<4;++rr){
                    const int kv = kv0 + nt*16 + lg*4 + rr;
                    if (kv > qrow) s4[nt][rr] = -1e30f;
                }
        }

        float pm;
        {
            float m0 = fmaxf(fmaxf(s4[0][0],s4[0][1]), fmaxf(s4[0][2],s4[0][3]));
            float m1 = fmaxf(fmaxf(s4[1][0],s4[1][1]), fmaxf(s4[1][2],s4[1][3]));
            float m2 = fmaxf(fmaxf(s4[2][0],s4[2][1]), fmaxf(s4[2][2],s4[2][3]));
            float m3 = fmaxf(fmaxf(s4[3][0],s4[3][1]), fmaxf(s4[3][2],s4[3][3]));
            pm = fmaxf(fmaxf(m0,m1), fmaxf(m2,m3));
        }
        pm = fmaxf(pm, __shfl_xor(pm, 16));
        pm = fmaxf(pm, __shfl_xor(pm, 32));
        if (pm > mrun + 8.0f){
            const float scl = exp2f(mrun - pm);
            mrun = pm; lrun *= scl;
            #pragma unroll
            for (int dt=0;dt<4;++dt)
                #pragma unroll
                for (int j=0;j<4;++j) o[dt][j] *= scl;
        }
        float rs = 0.f;
        #pragma unroll
        for (int nt=0;nt<4;++nt)
            #pragma unroll
            for (int rr=0;rr<4;++rr){
                const float pv = exp2f(s4[nt][rr] - mrun);
                s4[nt][rr] = pv; rs += pv;
            }
        rs += __shfl_xor(rs, 16);
        rs += __shfl_xor(rs, 32);
        lrun += rs;

        #pragma unroll
        for (int nt=0;nt<4;++nt){
            u16x4 pk;
            #pragma unroll
            for (int rr=0;rr<4;++rr) pk[rr] = (unsigned short)f2bf(s4[nt][rr]);
            *reinterpret_cast<u16x4*>(pw + l15*128 + ((nt*32 + lg*8) ^ ((l15&7)<<4))) = pk;
        }

        __builtin_amdgcn_s_setprio(1);
        #pragma unroll
        for (int ks=0;ks<2;++ks){
            bf16x8 pf = *reinterpret_cast<const bf16x8*>(pw + l15*128 + ((ks*64 + lg*16) ^ ((l15&7)<<4)));
            #pragma unroll
            for (int dt=0;dt<4;++dt)
                o[dt] = __builtin_amdgcn_mfma_f32_16x16x32_bf16(vf[ks*4+dt], pf, o[dt], 0,0,0);
        }
        __builtin_amdgcn_s_setprio(0);
    };

    for (int u = w; u < NU; u += 4){
        const bool isA = (u < nA);
        const int kvt = isA ? u : (u - nA);
        const int kv0 = kvt*64;
        const bool diag = isA ? (kvt == nA-1) : (kvt == nB-1);

        #pragma unroll
        for (int ks=0;ks<2;++ks)
            #pragma unroll
            for (int dt=0;dt<4;++dt)
                vf[ks*4+dt] = *reinterpret_cast<const bf16x8*>(Vb + (size_t)(dt*16+l15)*T_ + kv0 + ks*32 + lg*8);

        const int un = u + 4;
        const bool hasN = un < NU;
        const int kv0n = hasN ? ((un < nA ? un : un - nA) * 64) : 0;

        if (isA) body(oA, mA, lA, qA0, qA1, qrA, kv0, diag, hasN, kv0n);
        else     body(oB, mB, lB, qB0, qB1, qrB, kv0, diag, hasN, kv0n);
    }

    #pragma unroll
    for (int dt=0;dt<4;++dt){
        *reinterpret_cast<f32x4*>(&Oorg[w][0][l15*64 + dt*16 + lg*4]) = oA[dt];
        *reinterpret_cast<f32x4*>(&Oorg[w][1][l15*64 + dt*16 + lg*4]) = oB[dt];
    }
    if (lg == 0){
        Morg[w][0][l15] = mA; Lorg[w][0][l15] = lA;
        Morg[w][1][l15] = mB; Lorg[w][1][l15] = lB;
    }
    __syncthreads();
    {
        const int h = tid>>7, q = (tid>>3)&15, d0 = (tid&7)*8;
        const float m0=Morg[0][h][q], m1=Morg[1][h][q], m2=Morg[2][h][q], m3=Morg[3][h][q];
        const float M = fmaxf(fmaxf(m0,m1), fmaxf(m2,m3));
        const float a0=exp2f(m0-M), a1=exp2f(m1-M), a2=exp2f(m2-M), a3=exp2f(m3-M);
        const float L = a0*Lorg[0][h][q] + a1*Lorg[1][h][q] + a2*Lorg[2][h][q] + a3*Lorg[3][h][q];
        const float inv = 1.0f / L;
        const int s = h ? sB : sA;
        float* op = out + batchoff + (size_t)(s*16 + q)*64 + d0;
        #pragma unroll
        for (int j=0;j<8;++j){
            const float v = a0*Oorg[0][h][q*64+d0+j] + a1*Oorg[1][h][q*64+d0+j]
                          + a2*Oorg[2][h][q*64+d0+j] + a3*Oorg[3][h][q*64+d0+j];
            op[j] = v * inv;
        }
    }
}

extern "C" void kernel_launch(void* const* d_in, const int* in_sizes, int n_in,
                              void* d_out, int out_size, void* d_ws, size_t ws_size,
                              hipStream_t stream) {
    const float* x  = (const float*)d_in[0];
    const float* Wq = (const float*)d_in[1];
    const float* Wk = (const float*)d_in[2];
    const float* Wv = (const float*)d_in[3];
    float* out = (float*)d_out;

    __hip_bfloat16* Wfrag = (__hip_bfloat16*)d_ws;              // 384 KB
    __hip_bfloat16* Qb  = Wfrag + (size_t)24576*8;              // [B*T,64] (pre-scaled)
    __hip_bfloat16* Kb  = Qb + (size_t)B_*T_*64;                // [B*T,64]
    __hip_bfloat16* VTb = Kb + (size_t)B_*T_*64;                // [B][64][T]

    wconv_kernel<<<96, 256, 0, stream>>>(Wq, Wk, Wv, Wfrag);
    proj_kernel<<<512, 384, 0, stream>>>(x, Wfrag, Qb, Kb, VTb);
    fattn_kernel<<<512, 256, 0, stream>>>(Qb, Kb, VTb, out);
}